// Round 1
// baseline (191.887 us; speedup 1.0000x reference)
//
#include <hip/hip_runtime.h>
#include <hip/hip_bf16.h>

// Problem constants (fixed by setup_inputs): B=4, N=16384, M=128, C=128, S=512.
// Output layout (float32): pooled (B*M*S*(C+3)) then empty_flag (B*M) as 0.0/1.0.
#define BB   4
#define NN   16384
#define MM   128
#define CC   128
#define SS   512
#define CH   (CC + 3)      // 131
#define BM   (BB * MM)     // 512
#define WAVES 8            // waves per box in kernel A
#define CHUNK (NN / WAVES) // 2048 points per wave

// Session lessons (keep):
//  R5: fusing A+B into one kernel loses 8x gather TLP -> +20us. Don't.
//  R6: nontemporal output stores -> +7us. Don't.
//  R7: vectorizing A's point loads was neutral -> A is not VMEM-issue-bound.
//  R8: B's naive row-major LDS staging had 4-8 way bank conflicts on the
//      stride-16B ds_write_b32 pattern (only 8 of 32 banks reachable when
//      dword-index bits[1:0] are frozen) -> was dropped for direct stores.
//  R9 (this round): direct dword stores at 16-B lane stride are quarter-density
//      (each 128B line needs 4 instructions, ~8 lines touched per instr, rows
//      misaligned at 12k mod 16 so float4 is impossible row-locally). Re-add
//      LDS staging but with a FULL 5-bit XOR swizzle f(dw)=dw^((dw>>5)&31):
//      involution, stays inside each 32-dword block, and (unlike a 16B-granule
//      swizzle) perturbs bank bits[1:0], so both the row-major write pattern
//      (131k+3+4j+c) and the flat read pattern (4t+c) spread across all 32
//      banks. Output then leaves as dense 16B-aligned dwordx4 over the chunk's
//      contiguous 16768-B span (16768 % 16 == 0).
#define SWZ(d) ((d) ^ (((d) >> 5) & 31))

// ---------------------------------------------------------------------------
// Kernel A: one block (8 waves, 512 thr) per box.  (unchanged this round)
// Each lane owns 4 consecutive points (48 B = 3 aligned float4 loads).
// Stable compaction: group point order is (lane t major, u minor) = 4t+u, so
// pos = cnt + sum_u' popcll(M[u'] & lower(t)) + popc(m & ((1<<u)-1)).
// Waves merge by prefix offsets (stable), wrap-fill idx[k]=idx[k%cnt].
// Rotation test in double (true value >> fp32 ref roundoff); z-test fp32
// bit-identical to numpy.
// ---------------------------------------------------------------------------
__global__ __launch_bounds__(512)
void box_sample_kernel(const float* __restrict__ points,  // (B,N,3)
                       const float* __restrict__ boxes,   // (B,M,7)
                       int*  __restrict__ idx_ws,         // (BM,SS)
                       int*  __restrict__ cnt_ws,         // (BM)
                       float* __restrict__ flag_out)      // (BM)
{
    const int box  = blockIdx.x;          // b*MM + m
    const int b    = box >> 7;            // MM = 128
    const int lane = threadIdx.x & 63;
    const int w    = threadIdx.x >> 6;    // wave 0..7

    const float4* P4 = (const float4*)(points + (size_t)b * NN * 3);
    const float*  bx = boxes + (size_t)box * 7;

    const float cx = bx[0], cy = bx[1], cz = bx[2];
    const float dx = bx[3], dy = bx[4], dz = bx[5], rz = bx[6];

    const float  czc = cz + dz * 0.5f;     // exact
    const float  hz  = dz * 0.5f;          // exact
    const double ca  = cos(-(double)rz);
    const double sa  = sin(-(double)rz);
    const double hx  = (double)dx * 0.5;
    const double hy  = (double)dy * 0.5;

    __shared__ int s_part[WAVES][SS];     // 16 KB
    __shared__ int s_cnt[WAVES];
    __shared__ int s_idx[SS];

    int cnt = 0;
    const int pbase = w * CHUNK;
    for (int i0 = 0; i0 < CHUNK; i0 += 256) {     // 8 outer iterations
        const int pt0 = pbase + i0 + 4 * lane;    // first of this lane's 4 points
        const int f4b = (pt0 * 3) >> 2;           // pt0 % 4 == 0 -> exact
        const float4 q0 = P4[f4b + 0];   // p0.x p0.y p0.z p1.x
        const float4 q1 = P4[f4b + 1];   // p1.y p1.z p2.x p2.y
        const float4 q2 = P4[f4b + 2];   // p2.z p3.x p3.y p3.z
        const float px[4] = {q0.x, q0.w, q1.z, q2.y};
        const float py[4] = {q0.y, q1.x, q1.w, q2.z};
        const float pz[4] = {q0.z, q1.y, q2.x, q2.w};

        unsigned m = 0;
        #pragma unroll
        for (int u = 0; u < 4; ++u) {
            const double sx = (double)px[u] - (double)cx;
            const double sy = (double)py[u] - (double)cy;
            const float  szf = pz[u] - czc;
            const double lx = sx * ca - sy * sa;
            const double ly = sx * sa + sy * ca;
            const bool inside = (fabs(lx) < hx) && (fabs(ly) < hy) && (fabsf(szf) <= hz);
            m |= (unsigned)inside << u;
        }

        unsigned long long M[4];
        #pragma unroll
        for (int u = 0; u < 4; ++u) M[u] = __ballot((m >> u) & 1u);

        const unsigned long long lower = (1ull << lane) - 1ull;
        int lanebase = cnt;
        #pragma unroll
        for (int u = 0; u < 4; ++u) lanebase += __popcll(M[u] & lower);

        #pragma unroll
        for (int u = 0; u < 4; ++u) {
            if ((m >> u) & 1u) {
                const int pos = lanebase + __builtin_popcount(m & ((1u << u) - 1u));
                if (pos < SS) s_part[w][pos] = pt0 + u;
            }
        }
        #pragma unroll
        for (int u = 0; u < 4; ++u) cnt += __popcll(M[u]);
    }
    if (lane == 0) s_cnt[w] = cnt;
    __syncthreads();

    int c[WAVES], off[WAVES];
    int total = 0;
    #pragma unroll
    for (int q = 0; q < WAVES; ++q) { c[q] = s_cnt[q]; off[q] = total; total += c[q]; }

    // merge segments into first min(total,SS) slots, stable order
    for (int k = threadIdx.x; k < SS; k += 512) {
        int v = 0;
        #pragma unroll
        for (int q = 0; q < WAVES; ++q) {
            const int r = k - off[q];
            if (r >= 0 && r < c[q]) v = s_part[q][r];
        }
        s_idx[k] = v;
    }
    __syncthreads();

    if (total > 0 && total < SS) {
        for (int k = total + threadIdx.x; k < SS; k += 512)
            s_idx[k] = s_idx[k % total];
        __syncthreads();
    }

    int* dst = idx_ws + (size_t)box * SS;
    for (int k = threadIdx.x; k < SS; k += 512) dst[k] = s_idx[k];
    if (threadIdx.x == 0) {
        cnt_ws[box]   = total;
        flag_out[box] = (total == 0) ? 1.0f : 0.0f;
    }
}

// ---------------------------------------------------------------------------
// Kernel B: gather with swizzled-LDS staging -> dense aligned float4 stores.
// Grid (512 boxes, 16 chunks of 32 samples); 256 threads = 8 half-waves.
// Phase 1 (unchanged, R7-verified): each half-wave owns 4 samples; 4
//   independent float4 gathers issued back-to-back (max MLP).
// Phase 2: stage the chunk's 32x131 dwords into LDS at SWZ()'d addresses.
//   b32 writes at lane-stride 16B would be 8-way-conflicted raw (R8); the
//   5-bit XOR spreads them across all 32 banks (~<=3-way worst case).
// Phase 3: block cooperatively re-reads flat (SWZ'd b32 x4, same conflict-free
//   argument) and stores the contiguous 16768-B chunk span as aligned
//   global_store_dwordx4 — full-density lines instead of quarter-density.
// ---------------------------------------------------------------------------
__global__ __launch_bounds__(256)
void gather_kernel(const float* __restrict__ points,   // (B,N,3)
                   const float* __restrict__ feats,    // (B,N,C)
                   const int*   __restrict__ idx_ws,   // (BM,SS)
                   const int*   __restrict__ cnt_ws,   // (BM)
                   float* __restrict__ out)            // (BM,SS,CH)
{
    const int box   = blockIdx.x;         // 0..511
    const int chunk = blockIdx.y;         // 0..15
    const int b     = box >> 7;
    const int tid   = threadIdx.x;
    const int hw    = tid >> 5;           // half-wave 0..7
    const int j     = tid & 31;           // lane in half-wave

    __shared__ float s_out[32 * CH];      // 4192 dwords = 16768 B (swizzle is
                                          // block-local: stays in range)

    const float scale = (cnt_ws[box] > 0) ? 1.0f : 0.0f;
    const int* idxp = idx_ws + (size_t)box * SS + chunk * 32;

    int idx[4];
    #pragma unroll
    for (int s = 0; s < 4; ++s) idx[s] = idxp[hw + s * 8];

    const float4* F4 = (const float4*)(feats + (size_t)b * NN * CC);
    const float*  Pb = points + (size_t)b * NN * 3;

    float4 v[4];
    #pragma unroll
    for (int s = 0; s < 4; ++s) v[s] = F4[idx[s] * 32 + j];

    float p[4];
    #pragma unroll
    for (int s = 0; s < 4; ++s) p[s] = (j < 3) ? Pb[idx[s] * 3 + j] : 0.0f;

    // Phase 2: swizzled staging. Row k = hw + s*8 owns dwords [k*131, k*131+131).
    #pragma unroll
    for (int s = 0; s < 4; ++s) {
        const int k    = hw + s * 8;
        const int base = k * CH + 3 + 4 * j;
        s_out[SWZ(base + 0)] = v[s].x * scale;
        s_out[SWZ(base + 1)] = v[s].y * scale;
        s_out[SWZ(base + 2)] = v[s].z * scale;
        s_out[SWZ(base + 3)] = v[s].w * scale;
        if (j < 3) s_out[SWZ(k * CH + j)] = p[s] * scale;
    }
    __syncthreads();

    // Phase 3: dense aligned output. Chunk span start = 16768 B * (16*box+chunk),
    // 16B-aligned; 1048 float4s covered by 256 threads (4-5 iters each).
    float* dst = out + (size_t)box * SS * CH + (size_t)chunk * 32 * CH;
    for (int t = tid; t < (32 * CH) / 4; t += 256) {
        const int dw = 4 * t;
        float4 o;
        o.x = s_out[SWZ(dw + 0)];
        o.y = s_out[SWZ(dw + 1)];
        o.z = s_out[SWZ(dw + 2)];
        o.w = s_out[SWZ(dw + 3)];
        ((float4*)dst)[t] = o;
    }
}

extern "C" void kernel_launch(void* const* d_in, const int* in_sizes, int n_in,
                              void* d_out, int out_size, void* d_ws, size_t ws_size,
                              hipStream_t stream) {
    const float* points = (const float*)d_in[0];
    const float* feats  = (const float*)d_in[1];
    const float* boxes  = (const float*)d_in[2];
    // d_in[3] = num_sampled_points, fixed at 512 by setup_inputs.

    int*  idx_ws = (int*)d_ws;                       // BM*SS ints = 1 MiB
    int*  cnt_ws = idx_ws + (size_t)BM * SS;         // BM ints
    float* out      = (float*)d_out;
    float* flag_out = out + (size_t)BM * SS * CH;    // empty_flag as float 0/1

    box_sample_kernel<<<BM, 512, 0, stream>>>(points, boxes, idx_ws, cnt_ws, flag_out);
    dim3 ggrid(BM, SS / 32);
    gather_kernel<<<ggrid, 256, 0, stream>>>(points, feats, idx_ws, cnt_ws, out);
}

// Round 2
// 190.985 us; speedup vs baseline: 1.0047x; 1.0047x over previous
//
#include <hip/hip_runtime.h>
#include <hip/hip_bf16.h>

// Problem constants (fixed by setup_inputs): B=4, N=16384, M=128, C=128, S=512.
// Output layout (float32): pooled (B*M*S*(C+3)) then empty_flag (B*M) as 0.0/1.0.
#define BB   4
#define NN   16384
#define MM   128
#define CC   128
#define SS   512
#define CH   (CC + 3)      // 131
#define BM   (BB * MM)     // 512
#define WAVES 8            // waves per box in kernel A
#define CHUNK (NN / WAVES) // 2048 points per wave

// Session lessons (keep):
//  R5: fusing A+B into one kernel loses 8x gather TLP -> +20us. Don't.
//  R6: nontemporal output stores -> +7us. Don't.
//  R7: vectorizing A's point loads was neutral -> A is not VMEM-issue-bound.
//  R8: B's naive row-major LDS staging had 4-8 way bank conflicts on the
//      stride-16B ds_write_b32 pattern -> was dropped for direct stores.
//  R9: swizzled-LDS staging (SWZ below) + dense dwordx4 stores: 195.4->191.9us.
//      Small delta => B is NOT store-transaction-bound; it's read/cache-bound.
//  R10 (this round): B's random 512B-row gathers hit an 8MB-per-batch feature
//      table. Default dispatch round-robins workgroups over 8 XCDs, so every
//      4MB XCD-L2 sees all 4 batches (32MB working set, ~12% hit). Bijective
//      remap: XCD = flat%8 (HW round-robin), put batch b on XCD pair
//      {2b,2b+1} -> each L2 serves one 8MB table (~50% hit). Predict gather
//      -10-20%; worst case it's a harmless reshuffle (bijection).
#define SWZ(d) ((d) ^ (((d) >> 5) & 31))

// ---------------------------------------------------------------------------
// Kernel A: one block (8 waves, 512 thr) per box.  (unchanged this round)
// Each lane owns 4 consecutive points (48 B = 3 aligned float4 loads).
// Stable compaction: group point order is (lane t major, u minor) = 4t+u, so
// pos = cnt + sum_u' popcll(M[u'] & lower(t)) + popc(m & ((1<<u)-1)).
// Waves merge by prefix offsets (stable), wrap-fill idx[k]=idx[k%cnt].
// Rotation test in double (true value >> fp32 ref roundoff); z-test fp32
// bit-identical to numpy.
// ---------------------------------------------------------------------------
__global__ __launch_bounds__(512)
void box_sample_kernel(const float* __restrict__ points,  // (B,N,3)
                       const float* __restrict__ boxes,   // (B,M,7)
                       int*  __restrict__ idx_ws,         // (BM,SS)
                       int*  __restrict__ cnt_ws,         // (BM)
                       float* __restrict__ flag_out)      // (BM)
{
    const int box  = blockIdx.x;          // b*MM + m
    const int b    = box >> 7;            // MM = 128
    const int lane = threadIdx.x & 63;
    const int w    = threadIdx.x >> 6;    // wave 0..7

    const float4* P4 = (const float4*)(points + (size_t)b * NN * 3);
    const float*  bx = boxes + (size_t)box * 7;

    const float cx = bx[0], cy = bx[1], cz = bx[2];
    const float dx = bx[3], dy = bx[4], dz = bx[5], rz = bx[6];

    const float  czc = cz + dz * 0.5f;     // exact
    const float  hz  = dz * 0.5f;          // exact
    const double ca  = cos(-(double)rz);
    const double sa  = sin(-(double)rz);
    const double hx  = (double)dx * 0.5;
    const double hy  = (double)dy * 0.5;

    __shared__ int s_part[WAVES][SS];     // 16 KB
    __shared__ int s_cnt[WAVES];
    __shared__ int s_idx[SS];

    int cnt = 0;
    const int pbase = w * CHUNK;
    for (int i0 = 0; i0 < CHUNK; i0 += 256) {     // 8 outer iterations
        const int pt0 = pbase + i0 + 4 * lane;    // first of this lane's 4 points
        const int f4b = (pt0 * 3) >> 2;           // pt0 % 4 == 0 -> exact
        const float4 q0 = P4[f4b + 0];   // p0.x p0.y p0.z p1.x
        const float4 q1 = P4[f4b + 1];   // p1.y p1.z p2.x p2.y
        const float4 q2 = P4[f4b + 2];   // p2.z p3.x p3.y p3.z
        const float px[4] = {q0.x, q0.w, q1.z, q2.y};
        const float py[4] = {q0.y, q1.x, q1.w, q2.z};
        const float pz[4] = {q0.z, q1.y, q2.x, q2.w};

        unsigned m = 0;
        #pragma unroll
        for (int u = 0; u < 4; ++u) {
            const double sx = (double)px[u] - (double)cx;
            const double sy = (double)py[u] - (double)cy;
            const float  szf = pz[u] - czc;
            const double lx = sx * ca - sy * sa;
            const double ly = sx * sa + sy * ca;
            const bool inside = (fabs(lx) < hx) && (fabs(ly) < hy) && (fabsf(szf) <= hz);
            m |= (unsigned)inside << u;
        }

        unsigned long long M[4];
        #pragma unroll
        for (int u = 0; u < 4; ++u) M[u] = __ballot((m >> u) & 1u);

        const unsigned long long lower = (1ull << lane) - 1ull;
        int lanebase = cnt;
        #pragma unroll
        for (int u = 0; u < 4; ++u) lanebase += __popcll(M[u] & lower);

        #pragma unroll
        for (int u = 0; u < 4; ++u) {
            if ((m >> u) & 1u) {
                const int pos = lanebase + __builtin_popcount(m & ((1u << u) - 1u));
                if (pos < SS) s_part[w][pos] = pt0 + u;
            }
        }
        #pragma unroll
        for (int u = 0; u < 4; ++u) cnt += __popcll(M[u]);
    }
    if (lane == 0) s_cnt[w] = cnt;
    __syncthreads();

    int c[WAVES], off[WAVES];
    int total = 0;
    #pragma unroll
    for (int q = 0; q < WAVES; ++q) { c[q] = s_cnt[q]; off[q] = total; total += c[q]; }

    // merge segments into first min(total,SS) slots, stable order
    for (int k = threadIdx.x; k < SS; k += 512) {
        int v = 0;
        #pragma unroll
        for (int q = 0; q < WAVES; ++q) {
            const int r = k - off[q];
            if (r >= 0 && r < c[q]) v = s_part[q][r];
        }
        s_idx[k] = v;
    }
    __syncthreads();

    if (total > 0 && total < SS) {
        for (int k = total + threadIdx.x; k < SS; k += 512)
            s_idx[k] = s_idx[k % total];
        __syncthreads();
    }

    int* dst = idx_ws + (size_t)box * SS;
    for (int k = threadIdx.x; k < SS; k += 512) dst[k] = s_idx[k];
    if (threadIdx.x == 0) {
        cnt_ws[box]   = total;
        flag_out[box] = (total == 0) ? 1.0f : 0.0f;
    }
}

// ---------------------------------------------------------------------------
// Kernel B: gather with swizzled-LDS staging -> dense aligned float4 stores.
// Grid: 8192 flat workgroups, XCD-affinity remapped (R10). 256 threads =
// 8 half-waves; each half-wave owns 4 samples (4 independent float4 gathers,
// max MLP per R5/R7 lessons), stages via SWZ'd LDS (R9), leaves as dense
// aligned dwordx4 over the chunk's contiguous 16768-B span.
// ---------------------------------------------------------------------------
__global__ __launch_bounds__(256)
void gather_kernel(const float* __restrict__ points,   // (B,N,3)
                   const float* __restrict__ feats,    // (B,N,C)
                   const int*   __restrict__ idx_ws,   // (BM,SS)
                   const int*   __restrict__ cnt_ws,   // (BM)
                   float* __restrict__ out)            // (BM,SS,CH)
{
    // R10 XCD-affinity decode: flat id -> (batch, m, chunk) such that batch b
    // lands only on XCDs {2b, 2b+1} under HW round-robin (XCD = flat % 8).
    // Bijection over [0, 8192): r=flat&7 -> b=r>>1; s2=(flat>>3)*2+(r&1)
    // -> m = s2 & 127, chunk = s2 >> 7.
    const int flat  = blockIdx.x;
    const int r     = flat & 7;
    const int b     = r >> 1;
    const int s2    = ((flat >> 3) << 1) | (r & 1);
    const int m     = s2 & (MM - 1);
    const int chunk = s2 >> 7;            // 0..15
    const int box   = (b << 7) + m;

    const int tid   = threadIdx.x;
    const int hw    = tid >> 5;           // half-wave 0..7
    const int j     = tid & 31;           // lane in half-wave

    __shared__ float s_out[32 * CH];      // 4192 dwords = 16768 B (swizzle is
                                          // block-local: stays in range)

    const float scale = (cnt_ws[box] > 0) ? 1.0f : 0.0f;
    const int* idxp = idx_ws + (size_t)box * SS + chunk * 32;

    int idx[4];
    #pragma unroll
    for (int s = 0; s < 4; ++s) idx[s] = idxp[hw + s * 8];

    const float4* F4 = (const float4*)(feats + (size_t)b * NN * CC);
    const float*  Pb = points + (size_t)b * NN * 3;

    float4 v[4];
    #pragma unroll
    for (int s = 0; s < 4; ++s) v[s] = F4[idx[s] * 32 + j];

    float p[4];
    #pragma unroll
    for (int s = 0; s < 4; ++s) p[s] = (j < 3) ? Pb[idx[s] * 3 + j] : 0.0f;

    // Phase 2: swizzled staging. Row k = hw + s*8 owns dwords [k*131, k*131+131).
    #pragma unroll
    for (int s = 0; s < 4; ++s) {
        const int k    = hw + s * 8;
        const int base = k * CH + 3 + 4 * j;
        s_out[SWZ(base + 0)] = v[s].x * scale;
        s_out[SWZ(base + 1)] = v[s].y * scale;
        s_out[SWZ(base + 2)] = v[s].z * scale;
        s_out[SWZ(base + 3)] = v[s].w * scale;
        if (j < 3) s_out[SWZ(k * CH + j)] = p[s] * scale;
    }
    __syncthreads();

    // Phase 3: dense aligned output. Chunk span start = 16768 B * (16*box+chunk),
    // 16B-aligned; 1048 float4s covered by 256 threads (4-5 iters each).
    float* dst = out + (size_t)box * SS * CH + (size_t)chunk * 32 * CH;
    for (int t = tid; t < (32 * CH) / 4; t += 256) {
        const int dw = 4 * t;
        float4 o;
        o.x = s_out[SWZ(dw + 0)];
        o.y = s_out[SWZ(dw + 1)];
        o.z = s_out[SWZ(dw + 2)];
        o.w = s_out[SWZ(dw + 3)];
        ((float4*)dst)[t] = o;
    }
}

extern "C" void kernel_launch(void* const* d_in, const int* in_sizes, int n_in,
                              void* d_out, int out_size, void* d_ws, size_t ws_size,
                              hipStream_t stream) {
    const float* points = (const float*)d_in[0];
    const float* feats  = (const float*)d_in[1];
    const float* boxes  = (const float*)d_in[2];
    // d_in[3] = num_sampled_points, fixed at 512 by setup_inputs.

    int*  idx_ws = (int*)d_ws;                       // BM*SS ints = 1 MiB
    int*  cnt_ws = idx_ws + (size_t)BM * SS;         // BM ints
    float* out      = (float*)d_out;
    float* flag_out = out + (size_t)BM * SS * CH;    // empty_flag as float 0/1

    box_sample_kernel<<<BM, 512, 0, stream>>>(points, boxes, idx_ws, cnt_ws, flag_out);
    gather_kernel<<<BM * (SS / 32), 256, 0, stream>>>(points, feats, idx_ws, cnt_ws, out);
}